// Round 3
// baseline (493.987 us; speedup 1.0000x reference)
//
#include <hip/hip_runtime.h>

#define N_R   256
#define N_E   200000
#define N_T   1000000
#define B     32
#define D_Q   768
#define D_IN  1280
#define OBJ_MASK 0x3FFFFu

#define F0CAP 32768
#define F1CAP 262144
#define F2CAP 786432

// wave-aggregated append of `key` to list when pred (exec-masked ballot)
__device__ inline void wave_append(bool pred, unsigned key, int* cnt,
                                   unsigned* list, int cap) {
    unsigned long long m = __ballot(pred);
    if (!m) return;
    int lane = threadIdx.x & 63;
    int leader = __ffsll((unsigned long long)m) - 1;
    int tot = __popcll(m);
    int base = 0;
    if (lane == leader) base = atomicAdd(cnt, tot);
    base = __shfl(base, leader);
    if (pred) {
        int pre = __popcll(m & ((1ull << (unsigned)lane) - 1ull));
        int p = base + pre;
        if (p < cap) list[p] = key;
    }
}

// ---------------------------------------------------------------------------
// CSR build: histogram of subj into off[] (pre-zeroed by memset)
// ---------------------------------------------------------------------------
__global__ void k_hist(const int* __restrict__ subj, int* __restrict__ off) {
    int i = blockIdx.x * 256 + threadIdx.x;
    if (i < N_T) atomicAdd(&off[subj[i]], 1);
}

// in-place exclusive scan of off per 256-block; block totals to bsum
__global__ void k_scan1(int* __restrict__ off, int* __restrict__ bsum) {
    __shared__ int s[256];
    int t = threadIdx.x, i = blockIdx.x * 256 + t;
    int v = (i < N_E) ? off[i] : 0;
    s[t] = v;
    __syncthreads();
    for (int d = 1; d < 256; d <<= 1) {
        int n = (t >= d) ? s[t - d] : 0;
        __syncthreads();
        s[t] += n;
        __syncthreads();
    }
    if (i < N_E) off[i] = s[t] - v;           // exclusive within block
    if (t == 255) bsum[blockIdx.x] = s[t];    // inclusive block total
}

// scan block sums (NB=782 <= 1024), write bbase (exclusive) and off[N_E]=total
__global__ void k_scan2(const int* __restrict__ bsum, int* __restrict__ bbase,
                        int* __restrict__ off, int nb) {
    __shared__ int s[1024];
    int t = threadIdx.x;
    int v = (t < nb) ? bsum[t] : 0;
    s[t] = v;
    __syncthreads();
    for (int d = 1; d < 1024; d <<= 1) {
        int n = (t >= d) ? s[t - d] : 0;
        __syncthreads();
        s[t] += n;
        __syncthreads();
    }
    if (t < nb) bbase[t] = s[t] - v;
    if (t == nb - 1) off[N_E] = s[t];
}

// add block bases; init cur = off
__global__ void k_scan3(int* __restrict__ off, const int* __restrict__ bbase,
                        int* __restrict__ cur) {
    int i = blockIdx.x * 256 + threadIdx.x;
    if (i < N_E) {
        int v = off[i] + bbase[blockIdx.x];
        off[i] = v;
        cur[i] = v;
    }
}

// fill packed edges: (rel<<18)|obj at cur[subj]++
__global__ void k_fill(const int* __restrict__ subj, const int* __restrict__ rel,
                       const int* __restrict__ obj, int* __restrict__ cur,
                       unsigned* __restrict__ edges) {
    int i = blockIdx.x * 256 + threadIdx.x;
    if (i < N_T) {
        int s = subj[i];
        int pos = atomicAdd(&cur[s], 1);
        edges[pos] = ((unsigned)rel[i] << 18) | (unsigned)obj[i];
    }
}

// ---------------------------------------------------------------------------
// init: transpose x (B,N_E)->xT(N_E,B); append nonzero pairs to f0; zero bufB
// ---------------------------------------------------------------------------
__global__ void k_init(const float* __restrict__ x, float* __restrict__ xT,
                       unsigned* __restrict__ f0, int* __restrict__ cnt0,
                       float* __restrict__ bufB) {
    __shared__ float tile[64 * 33];
    int e0 = blockIdx.x * 64;
    int t  = threadIdx.x;
#pragma unroll
    for (int i = 0; i < 8; ++i) {
        int o = i * 256 + t;
        int b = o >> 6, e = o & 63;
        tile[e * 33 + b] = x[b * N_E + e0 + e];
    }
    __syncthreads();
#pragma unroll
    for (int i = 0; i < 8; ++i) {
        int o = i * 256 + t;
        int e = o >> 5, b = o & 31;
        float v = tile[e * 33 + b];
        xT[(e0 + e) * 32 + b] = v;
        wave_append(v != 0.f, (unsigned)(((e0 + e) << 5) | b), cnt0, f0, F0CAP);
    }
    float4 z = {0.f, 0.f, 0.f, 0.f};
    ((float4*)bufB)[blockIdx.x * 512 + t]       = z;
    ((float4*)bufB)[blockIdx.x * 512 + 256 + t] = z;
}

// ---------------------------------------------------------------------------
// r-chain (unchanged from R2, verified)
// ---------------------------------------------------------------------------
__global__ void k_r0(const float* __restrict__ h_q, const float* __restrict__ W_inf,
                     float* __restrict__ rT0) {
    __shared__ float hs[32 * 257];
    __shared__ float red[256];
    int t = threadIdx.x, rel = blockIdx.x;
    int b = t & 31, kp = t >> 5;
    float acc = 0.f;
    for (int c = 0; c < 3; ++c) {
        __syncthreads();
#pragma unroll
        for (int i = 0; i < 32; ++i)
            hs[i * 257 + t] = h_q[i * D_Q + c * 256 + t];
        __syncthreads();
        const float* w = &W_inf[rel * D_IN + c * 256 + kp * 32];
#pragma unroll
        for (int i = 0; i < 32; ++i)
            acc += w[i] * hs[b * 257 + kp * 32 + i];
    }
    red[t] = acc;
    __syncthreads();
    if (t < 32) {
        float s = 0.f;
        for (int q = 0; q < 8; ++q) s += red[q * 32 + t];
        rT0[rel * 32 + t] = s;
    }
}

__global__ void k_r12(const float* __restrict__ W_inf, const float* __restrict__ rT0,
                      const float* __restrict__ rPrev, float* __restrict__ rOut,
                      int hop2) {
    __shared__ float red[256];
    int t = threadIdx.x, rel = blockIdx.x;
    int b = t & 31, jp = t >> 5;
    const float* w2 = &W_inf[rel * D_IN + D_Q];
    float acc = 0.f;
#pragma unroll 8
    for (int jj = 0; jj < 32; ++jj) {
        int j = jp * 32 + jj;
        acc += w2[j] * rPrev[j * 32 + b];
    }
    if (hop2) {
        const float* w3 = w2 + N_R;
#pragma unroll 8
        for (int jj = 0; jj < 32; ++jj) {
            int j = jp * 32 + jj;
            acc += w3[j] * rT0[j * 32 + b];
        }
    }
    red[t] = acc;
    __syncthreads();
    if (t < 32) {
        float s = rT0[rel * 32 + t];
        for (int q = 0; q < 8; ++q) s += red[q * 32 + t];
        rOut[rel * 32 + t] = s;
    }
}

__global__ void k_att(const float* __restrict__ h_q, const float* __restrict__ W_att,
                      const float* __restrict__ rT0, const float* __restrict__ rT1,
                      float* __restrict__ a_w) {
    __shared__ float p0[256], p1[256], p2[256], p3[256];
    int t = threadIdx.x;
    int b = t & 31, p = t >> 5;
    float c0 = 0.f;
    for (int k = p * 96; k < p * 96 + 96; ++k) c0 += W_att[k] * h_q[b * D_Q + k];
    float s1 = 0.f, s2 = 0.f, s3 = 0.f;
    for (int j = p * 32; j < p * 32 + 32; ++j) {
        float w2 = W_att[D_Q + j], w3 = W_att[D_Q + N_R + j];
        float r0v = rT0[j * 32 + b], r1v = rT1[j * 32 + b];
        s1 += w2 * r0v; s2 += w2 * r1v; s3 += w3 * r0v;
    }
    p0[t] = c0; p1[t] = s1; p2[t] = s2; p3[t] = s3;
    __syncthreads();
    if (t < 32) {
        float C0 = 0.f, S1 = 0.f, S2 = 0.f, S3 = 0.f;
        for (int q = 0; q < 8; ++q) {
            C0 += p0[q * 32 + t]; S1 += p1[q * 32 + t];
            S2 += p2[q * 32 + t]; S3 += p3[q * 32 + t];
        }
        float c1 = C0 + S1, c2 = C0 + S2 + S3;
        float m  = fmaxf(C0, fmaxf(c1, c2));
        float e0 = __expf(C0 - m), e1 = __expf(c1 - m), e2 = __expf(c2 - m);
        float inv = 1.f / (e0 + e1 + e2);
        a_w[t] = e0 * inv; a_w[32 + t] = e1 * inv; a_w[64 + t] = e2 * inv;
    }
}

// ---------------------------------------------------------------------------
// hop over pair frontier: one thread per (e,b) pair, loop CSR edges of e.
// xOut[o,b] += v * rT[rel,b]; append (o,b) to fOut when cell was zero.
// ---------------------------------------------------------------------------
__global__ void k_hop(const float* __restrict__ xIn, const float* __restrict__ rT,
                      const int* __restrict__ off, const unsigned* __restrict__ edges,
                      const unsigned* __restrict__ fIn, const int* __restrict__ nIn,
                      int capIn, float* __restrict__ xOut,
                      unsigned* __restrict__ fOut, int* __restrict__ cntOut,
                      int capOut, int doAppend) {
    int n = *nIn; if (n > capIn) n = capIn;
    int stride = gridDim.x * 256;
    for (int idx = blockIdx.x * 256 + threadIdx.x; idx < n; idx += stride) {
        unsigned key = fIn[idx];
        int e = key >> 5, b = key & 31;
        float v = xIn[e * 32 + b];
        if (v != 0.f) {
            int s0 = off[e], s1 = off[e + 1];
            for (int p = s0; p < s1; ++p) {
                unsigned u = edges[p];
                int o = u & OBJ_MASK;
                float rv = rT[(u >> 18) * 32 + b];
                float old = unsafeAtomicAdd(&xOut[o * 32 + b], v * rv);
                if (doAppend)
                    wave_append(old == 0.f, (unsigned)((o << 5) | b),
                                cntOut, fOut, capOut);
            }
        }
    }
}

// ---------------------------------------------------------------------------
// sparse out update: out[b,e] += a_w[hop*32+b] * xbuf[e,b] over frontier pairs
// ---------------------------------------------------------------------------
__global__ void k_out_sp(const unsigned* __restrict__ f, const int* __restrict__ nIn,
                         int cap, const float* __restrict__ xbuf,
                         const float* __restrict__ a_w, int hop,
                         float* __restrict__ out) {
    int n = *nIn; if (n > cap) n = cap;
    int stride = gridDim.x * 256;
    for (int idx = blockIdx.x * 256 + threadIdx.x; idx < n; idx += stride) {
        unsigned key = f[idx];
        int e = key >> 5, b = key & 31;
        out[b * N_E + e] += a_w[hop * 32 + b] * xbuf[e * 32 + b];
    }
}

// ---------------------------------------------------------------------------
// dense final: out(B,N_E) += a2 * x3(N_E,B), transposed via LDS tile
// ---------------------------------------------------------------------------
__global__ void k_axpy(const float* __restrict__ xT, const float* __restrict__ a_w,
                       float* __restrict__ out) {
    __shared__ float tile[32 * 65];
    int e0 = blockIdx.x * 64;
    int t  = threadIdx.x;
#pragma unroll
    for (int i = 0; i < 8; ++i) {
        int o = i * 256 + t;
        int e = o >> 5, b = o & 31;
        tile[b * 65 + e] = xT[(e0 + e) * 32 + b];
    }
    __syncthreads();
#pragma unroll
    for (int i = 0; i < 8; ++i) {
        int o = i * 256 + t;
        int b = o >> 6, e = o & 63;
        out[b * N_E + e0 + e] += a_w[2 * 32 + b] * tile[b * 65 + e];
    }
}

extern "C" void kernel_launch(void* const* d_in, const int* in_sizes, int n_in,
                              void* d_out, int out_size, void* d_ws, size_t ws_size,
                              hipStream_t stream) {
    const float* x     = (const float*)d_in[0];
    const float* h_q   = (const float*)d_in[1];
    const float* W_inf = (const float*)d_in[2];
    const float* W_att = (const float*)d_in[3];
    const int*   subj  = (const int*)d_in[4];
    const int*   rel   = (const int*)d_in[5];
    const int*   obj   = (const int*)d_in[6];
    float* out = (float*)d_out;

    const size_t NEB = (size_t)N_E * B;   // 6.4e6
    float* bufA = (float*)d_ws;
    float* bufB = bufA + NEB;
    float* rT   = bufB + NEB;                       // 3*8192
    float* a_w  = rT + 3 * N_R * B;                 // 96
    int*   counters = (int*)(a_w + 96);             // 16
    int*   off  = counters + 16;                    // N_E+64
    int*   bsum = off + (N_E + 64);                 // 1024
    int*   bbase= bsum + 1024;                      // 1024
    unsigned* edges = (unsigned*)(bbase + 1024);    // 1M
    unsigned* f0 = edges + N_T;                     // F0CAP
    unsigned* f1 = f0 + F0CAP;                      // F1CAP
    int*      cur = (int*)f1;                       // alias (lifetime-disjoint)
    unsigned* f2 = f1 + F1CAP;                      // F2CAP

    const int TB  = N_E / 64;                 // 3125
    const int NTB = (N_T + 255) / 256;        // 3907
    const int NEBK= (N_E + 255) / 256;        // 782

    // zero deg/off, counters, out
    hipMemsetAsync(off, 0, (N_E + 64) * sizeof(int), stream);
    hipMemsetAsync(counters, 0, 16 * sizeof(int), stream);
    hipMemsetAsync(out, 0, NEB * sizeof(float), stream);

    // CSR build
    k_hist <<<NTB, 256, 0, stream>>>(subj, off);
    k_scan1<<<NEBK, 256, 0, stream>>>(off, bsum);
    k_scan2<<<1, 1024, 0, stream>>>(bsum, bbase, off, NEBK);
    k_scan3<<<NEBK, 256, 0, stream>>>(off, bbase, cur);
    k_fill <<<NTB, 256, 0, stream>>>(subj, rel, obj, cur, edges);

    // transpose + f0 frontier + zero bufB
    k_init<<<TB, 256, 0, stream>>>(x, bufA, f0, counters + 0, bufB);

    // relation / attention chain
    k_r0 <<<N_R, 256, 0, stream>>>(h_q, W_inf, rT);
    k_r12<<<N_R, 256, 0, stream>>>(W_inf, rT, rT, rT + N_R * B, 0);
    k_r12<<<N_R, 256, 0, stream>>>(W_inf, rT, rT + N_R * B, rT + 2 * N_R * B, 1);
    k_att<<<1, 256, 0, stream>>>(h_q, W_att, rT, rT + N_R * B, a_w);

    // hop 0: bufA -> bufB, frontier f0 -> f1
    k_hop<<<1024, 256, 0, stream>>>(bufA, rT, off, edges, f0, counters + 0, F0CAP,
                                    bufB, f1, counters + 1, F1CAP, 1);
    k_out_sp<<<1024, 256, 0, stream>>>(f1, counters + 1, F1CAP, bufB, a_w, 0, out);
    hipMemsetAsync(bufA, 0, NEB * sizeof(float), stream);

    // hop 1: bufB -> bufA, frontier f1 -> f2
    k_hop<<<1024, 256, 0, stream>>>(bufB, rT + N_R * B, off, edges, f1, counters + 1,
                                    F1CAP, bufA, f2, counters + 2, F2CAP, 1);
    k_out_sp<<<1024, 256, 0, stream>>>(f2, counters + 2, F2CAP, bufA, a_w, 1, out);
    hipMemsetAsync(bufB, 0, NEB * sizeof(float), stream);

    // hop 2: bufA -> bufB (no frontier append)
    k_hop<<<1024, 256, 0, stream>>>(bufA, rT + 2 * N_R * B, off, edges, f2,
                                    counters + 2, F2CAP, bufB,
                                    (unsigned*)0, (int*)0, 0, 0);

    // dense final: out += a2 * x3^T
    k_axpy<<<TB, 256, 0, stream>>>(bufB, a_w, out);
}

// Round 4
// 215.945 us; speedup vs baseline: 2.2876x; 2.2876x over previous
//
#include <hip/hip_runtime.h>

#define N_R   256
#define N_E   200000
#define N_T   1000000
#define B     32
#define D_Q   768
#define D_IN  1280

// ---------------------------------------------------------------------------
// mask0[e] = bitmask over b of (x[b,e] != 0). Coalesced column scan.
// ---------------------------------------------------------------------------
__global__ void k_mask0(const float* __restrict__ x, unsigned* __restrict__ mask0) {
    int e = blockIdx.x * 256 + threadIdx.x;
    if (e >= N_E) return;
    unsigned m = 0;
#pragma unroll 8
    for (int b = 0; b < 32; ++b)
        m |= (x[(size_t)b * N_E + e] != 0.f ? 1u : 0u) << b;
    mask0[e] = m;
}

// ---------------------------------------------------------------------------
// r0[rel,b] = W_inf[rel,0:768] . h_q[b,:]  — one rel per block (verified R2/R3)
// ---------------------------------------------------------------------------
__global__ void k_r0(const float* __restrict__ h_q, const float* __restrict__ W_inf,
                     float* __restrict__ rT0) {
    __shared__ float hs[32 * 257];
    __shared__ float red[256];
    int t = threadIdx.x, rel = blockIdx.x;
    int b = t & 31, kp = t >> 5;
    float acc = 0.f;
    for (int c = 0; c < 3; ++c) {
        __syncthreads();
#pragma unroll
        for (int i = 0; i < 32; ++i)
            hs[i * 257 + t] = h_q[i * D_Q + c * 256 + t];
        __syncthreads();
        const float* w = &W_inf[rel * D_IN + c * 256 + kp * 32];
#pragma unroll
        for (int i = 0; i < 32; ++i)
            acc += w[i] * hs[b * 257 + kp * 32 + i];
    }
    red[t] = acc;
    __syncthreads();
    if (t < 32) {
        float s = 0.f;
        for (int q = 0; q < 8; ++q) s += red[q * 32 + t];
        rT0[rel * 32 + t] = s;
    }
}

__global__ void k_r12(const float* __restrict__ W_inf, const float* __restrict__ rT0,
                      const float* __restrict__ rPrev, float* __restrict__ rOut,
                      int hop2) {
    __shared__ float red[256];
    int t = threadIdx.x, rel = blockIdx.x;
    int b = t & 31, jp = t >> 5;
    const float* w2 = &W_inf[rel * D_IN + D_Q];
    float acc = 0.f;
#pragma unroll 8
    for (int jj = 0; jj < 32; ++jj) {
        int j = jp * 32 + jj;
        acc += w2[j] * rPrev[j * 32 + b];
    }
    if (hop2) {
        const float* w3 = w2 + N_R;
#pragma unroll 8
        for (int jj = 0; jj < 32; ++jj) {
            int j = jp * 32 + jj;
            acc += w3[j] * rT0[j * 32 + b];
        }
    }
    red[t] = acc;
    __syncthreads();
    if (t < 32) {
        float s = rT0[rel * 32 + t];
        for (int q = 0; q < 8; ++q) s += red[q * 32 + t];
        rOut[rel * 32 + t] = s;
    }
}

__global__ void k_att(const float* __restrict__ h_q, const float* __restrict__ W_att,
                      const float* __restrict__ rT0, const float* __restrict__ rT1,
                      float* __restrict__ a_w) {
    __shared__ float p0[256], p1[256], p2[256], p3[256];
    int t = threadIdx.x;
    int b = t & 31, p = t >> 5;
    float c0 = 0.f;
    for (int k = p * 96; k < p * 96 + 96; ++k) c0 += W_att[k] * h_q[b * D_Q + k];
    float s1 = 0.f, s2 = 0.f, s3 = 0.f;
    for (int j = p * 32; j < p * 32 + 32; ++j) {
        float w2 = W_att[D_Q + j], w3 = W_att[D_Q + N_R + j];
        float r0v = rT0[j * 32 + b], r1v = rT1[j * 32 + b];
        s1 += w2 * r0v; s2 += w2 * r1v; s3 += w3 * r0v;
    }
    p0[t] = c0; p1[t] = s1; p2[t] = s2; p3[t] = s3;
    __syncthreads();
    if (t < 32) {
        float C0 = 0.f, S1 = 0.f, S2 = 0.f, S3 = 0.f;
        for (int q = 0; q < 8; ++q) {
            C0 += p0[q * 32 + t]; S1 += p1[q * 32 + t];
            S2 += p2[q * 32 + t]; S3 += p3[q * 32 + t];
        }
        float c1 = C0 + S1, c2 = C0 + S2 + S3;
        float m  = fmaxf(C0, fmaxf(c1, c2));
        float e0 = __expf(C0 - m), e1 = __expf(c1 - m), e2 = __expf(c2 - m);
        float inv = 1.f / (e0 + e1 + e2);
        a_w[t] = e0 * inv; a_w[32 + t] = e1 * inv; a_w[64 + t] = e2 * inv;
    }
}

// ---------------------------------------------------------------------------
// hop: 1 thread per triple, gated by subject activity mask.
// For each active batch bit b:
//   c = x[s,b] * rT[rel,b]
//   if HAS_NEXT: xOut[o,b] += c           (next hop's input, (N_E,B) layout)
//   out[b,o]   += aw[b] * c               (fused attention-weighted output)
// if HAS_NEXT: maskOut[o] |= m
// BN_LAYOUT: xIn is (B,N_E) for hop0 (original x), else (N_E,B).
// ---------------------------------------------------------------------------
template <bool BN_LAYOUT, bool HAS_NEXT>
__global__ void k_hop(const float* __restrict__ xIn,
                      const unsigned* __restrict__ maskIn,
                      const float* __restrict__ rT, const float* __restrict__ aw,
                      const int* __restrict__ subj, const int* __restrict__ rel,
                      const int* __restrict__ obj,
                      float* __restrict__ xOut, unsigned* __restrict__ maskOut,
                      float* __restrict__ outp) {
    int i = blockIdx.x * 256 + threadIdx.x;
    if (i >= N_T) return;
    int s = subj[i];
    unsigned m = maskIn[s];
    if (!m) return;
    int r = rel[i];
    int o = obj[i];
    const float* rrow = rT + r * 32;
    unsigned mm = m;
    while (mm) {
        int b = __ffs(mm) - 1;
        mm &= mm - 1;
        float v = BN_LAYOUT ? xIn[(size_t)b * N_E + s] : xIn[s * 32 + b];
        float c = v * rrow[b];
        if (HAS_NEXT) unsafeAtomicAdd(&xOut[o * 32 + b], c);
        unsafeAtomicAdd(&outp[(size_t)b * N_E + o], aw[b] * c);
    }
    if (HAS_NEXT) atomicOr(&maskOut[o], m);
}

extern "C" void kernel_launch(void* const* d_in, const int* in_sizes, int n_in,
                              void* d_out, int out_size, void* d_ws, size_t ws_size,
                              hipStream_t stream) {
    const float* x     = (const float*)d_in[0];
    const float* h_q   = (const float*)d_in[1];
    const float* W_inf = (const float*)d_in[2];
    const float* W_att = (const float*)d_in[3];
    const int*   subj  = (const int*)d_in[4];
    const int*   rel   = (const int*)d_in[5];
    const int*   obj   = (const int*)d_in[6];
    float* out = (float*)d_out;

    const size_t NEB = (size_t)N_E * B;            // 6.4e6 floats
    float*    bufA  = (float*)d_ws;                // x1, (N_E,B)
    float*    bufB  = bufA + NEB;                  // x2, (N_E,B)
    float*    rT    = bufB + NEB;                  // 3 * N_R * B
    float*    a_w   = rT + 3 * N_R * B;            // 96
    unsigned* mask1 = (unsigned*)(a_w + 96);       // N_E
    unsigned* mask2 = mask1 + N_E;                 // N_E (contiguous w/ mask1)
    unsigned* mask0 = mask2 + N_E;                 // N_E

    const int EB  = (N_E + 255) / 256;   // 782
    const int TBL = (N_T + 255) / 256;   // 3907

    // zero: x1+x2 buffers (one contiguous memset), mask1+mask2, out
    hipMemsetAsync(bufA, 0, 2 * NEB * sizeof(float), stream);
    hipMemsetAsync(mask1, 0, 2 * N_E * sizeof(unsigned), stream);
    hipMemsetAsync(out, 0, NEB * sizeof(float), stream);

    // activity mask of x
    k_mask0<<<EB, 256, 0, stream>>>(x, mask0);

    // relation / attention chain
    k_r0 <<<N_R, 256, 0, stream>>>(h_q, W_inf, rT);
    k_r12<<<N_R, 256, 0, stream>>>(W_inf, rT, rT, rT + N_R * B, 0);
    k_r12<<<N_R, 256, 0, stream>>>(W_inf, rT, rT + N_R * B, rT + 2 * N_R * B, 1);
    k_att<<<1, 256, 0, stream>>>(h_q, W_att, rT, rT + N_R * B, a_w);

    // hop 0: x (B,N_E) -> x1 (bufA), out += a0*contrib, mask0 -> mask1
    k_hop<true, true><<<TBL, 256, 0, stream>>>(x, mask0, rT, a_w,
                                               subj, rel, obj, bufA, mask1, out);
    // hop 1: x1 -> x2 (bufB), out += a1*contrib, mask1 -> mask2
    k_hop<false, true><<<TBL, 256, 0, stream>>>(bufA, mask1, rT + N_R * B, a_w + 32,
                                                subj, rel, obj, bufB, mask2, out);
    // hop 2: x2 -> out only (out += a2*contrib)
    k_hop<false, false><<<TBL, 256, 0, stream>>>(bufB, mask2, rT + 2 * N_R * B, a_w + 64,
                                                 subj, rel, obj, (float*)0,
                                                 (unsigned*)0, out);
}